// Round 10
// baseline (1228.973 us; speedup 1.0000x reference)
//
#include <hip/hip_runtime.h>
#include <hip/hip_bf16.h>
#include <math.h>

#define NT 34000
#define NTYPES 3
#define NMP 2
#define NE 300000
#define HH 8
#define DD 64
#define HD 512
#define AV 128
#define NCLS 8
#define NTGT 1000
#define NN (NTYPES*NT)
#define NBLK 133   // ceil(NT/256)
#define SCBLK 1172 // ceil(NE/256)
#define TSC (6*SCBLK)   // 7032 scatter blocks
#define TMM (3*532)     // 1596 mm64f blocks

typedef short short8 __attribute__((ext_vector_type(8)));
typedef float f32x4 __attribute__((ext_vector_type(4)));

__device__ __forceinline__ short f2bf(float f){
  unsigned u = __float_as_uint(f);
  unsigned r = u + 0x7FFFu + ((u>>16)&1u);
  return (short)(r>>16);
}
__device__ __forceinline__ float bf2f(short s){
  return __uint_as_float(((unsigned)(unsigned short)s)<<16);
}
__device__ __forceinline__ float fast_tanh(float x){
  x = fminf(15.f, fmaxf(-15.f, x));
  float t = __expf(2.f*x);
  return (t-1.f)/(t+1.f);
}

// beta = softmax over P of (mean tanh)·q, computed redundantly per-thread from accv slot
__device__ __forceinline__ void compute_beta(const float* __restrict__ av,
                                             const float* __restrict__ q,
                                             float* b0, float* b1){
  float s0=0.f, s1=0.f;
  #pragma unroll
  for(int c=0;c<32;c++){
    float4 a0=((const float4*)av)[c];
    float4 a1=((const float4*)(av+128))[c];
    float4 qq=((const float4*)q)[c];
    s0 += a0.x*qq.x+a0.y*qq.y+a0.z*qq.z+a0.w*qq.w;
    s1 += a1.x*qq.x+a1.y*qq.y+a1.z*qq.z+a1.w*qq.w;
  }
  s0 /= (float)NT; s1 /= (float)NT;
  float mm=fmaxf(s0,s1);
  float e0=__expf(s0-mm), e1=__expf(s1-mm);
  float d=e0+e1;
  *b0=e0/d; *b1=e1/d;
}

// ---------------- CSR build ----------------
__global__ void k_zero(int* __restrict__ p, int n){
  int i = blockIdx.x*256+threadIdx.x; if(i<n) p[i]=0;
}

__global__ void k_hist(const int* __restrict__ mp, int* __restrict__ counts){
  int e = blockIdx.x*256+threadIdx.x; int g = blockIdx.y;
  if(e>=NE) return;
  int i = g>>1;
  int dst = mp[((size_t)g*NE+e)*3] - i*NT;
  atomicAdd(&counts[g*NT+dst],1);
}

// block-level reduce: bsum[g][blk] = sum of counts[g][blk*256 .. +255]
__global__ __launch_bounds__(256) void k_blkred(const int* __restrict__ counts, int* __restrict__ bsum){
  int g=blockIdx.y, blk=blockIdx.x, t=threadIdx.x;
  int idx=blk*256+t;
  int v=(idx<NT)? counts[g*NT+idx]:0;
  #pragma unroll
  for(int off=32;off;off>>=1) v+=__shfl_down(v,off,64);
  __shared__ int sh[4];
  if((t&63)==0) sh[t>>6]=v;
  __syncthreads();
  if(t==0) bsum[g*NBLK+blk]=sh[0]+sh[1]+sh[2]+sh[3];
}

// exclusive scan of the 133 block sums per group (in place)
__global__ __launch_bounds__(256) void k_scansums(int* __restrict__ bsum){
  int g=blockIdx.x; int t=threadIdx.x;
  __shared__ int s[256];
  int v=(t<NBLK)? bsum[g*NBLK+t]:0;
  s[t]=v; __syncthreads();
  for(int off=1;off<256;off<<=1){
    int tmp=(t>=off)?s[t-off]:0; __syncthreads();
    s[t]+=tmp; __syncthreads();
  }
  if(t<NBLK) bsum[g*NBLK+t]=s[t]-v;
}

// rescan each chunk, add block prefix, write offs, zero counts for scatter reuse
__global__ __launch_bounds__(256) void k_scanapply(int* __restrict__ counts, const int* __restrict__ bsum,
                                                   int* __restrict__ offs){
  int g=blockIdx.y, blk=blockIdx.x, t=threadIdx.x;
  int idx=blk*256+t;
  int v=(idx<NT)? counts[g*NT+idx]:0;
  __shared__ int s[256];
  s[t]=v; __syncthreads();
  for(int off=1;off<256;off<<=1){
    int tmp=(t>=off)?s[t-off]:0; __syncthreads();
    s[t]+=tmp; __syncthreads();
  }
  int excl = s[t]-v + bsum[g*NBLK+blk];
  if(idx<NT){ offs[g*(NT+1)+idx]=excl; counts[g*NT+idx]=0; }
  if(idx==NT-1) offs[g*(NT+1)+NT]=excl+v;
}

// -------- pack fc weights (hi/lo split-bf16) + all 4 mpW mats (bf16) + zero accv ----
__global__ void k_packWall(const float* __restrict__ W0, const float* __restrict__ W1,
                           const float* __restrict__ W2, const float* __restrict__ WL,
                           const float* __restrict__ mpW,
                           short* __restrict__ p0, short* __restrict__ p1,
                           short* __restrict__ p2, short* __restrict__ pL,
                           short* __restrict__ bpk4, float* __restrict__ accv){
  int which = blockIdx.y;
  int tid = blockIdx.x*256+threadIdx.x;
  if(which<4){
    const float* W; short* wpk; int K;
    if(which==0){W=W0;wpk=p0;K=512;}
    else if(which==1){W=W1;wpk=p1;K=256;}
    else if(which==2){W=W2;wpk=p2;K=128;}
    else {W=WL;wpk=pL;K=512;}
    int nk = K>>5;
    int total = nk*256;
    if(tid>=total) return;
    int lane = tid&63; int c=(tid>>6)&3; int kt=tid>>8;
    int col = c*16 + (lane&15);
    int kbase = kt*32 + ((lane>>4)<<3);
    short8 hi, lo;
    #pragma unroll
    for(int j=0;j<8;j++){
      float w = W[(size_t)(kbase+j)*64+col];
      short h = f2bf(w); hi[j]=h;
      lo[j] = f2bf(w - bf2f(h));
    }
    ((short8*)wpk)[tid] = hi;
    ((short8*)wpk)[total+tid] = lo;
  } else {
    if(which==4 && tid<1024) accv[tid]=0.f;   // zero all 4 accv slots
    if(tid>=8192) return;
    // mpW slots used: (l,t) = (0,0),(0,1),(0,2),(1,0) -> flat 0,1,2,3 == which-4
    const float* W = mpW + (size_t)(which-4)*512*128;
    short* out = bpk4 + (size_t)(which-4)*65536;
    int lane=tid&63; int c=(tid>>6)&7; int t=tid>>9;
    int kbase = t*32 + ((lane>>4)<<3);
    int col = c*16 + (lane&15);
    short8 v;
    #pragma unroll
    for(int jj=0;jj<8;jj++) v[jj]=f2bf(W[(size_t)(kbase+jj)*128+col]);
    ((short8*)out)[tid]=v;
  }
}

// -------- FUSED: edge scatter (latency-bound) + per-type fc MFMA (compute-bound) ----
// Interleaved flat grid (period 27 = 22 scatter + 5 mm) so both populations are
// co-resident per CU and hide each other.
__global__ __launch_bounds__(256) void k_scmm(const int* __restrict__ mp, const int* __restrict__ offs,
    int* __restrict__ counts, int2* __restrict__ mids,
    const float* __restrict__ X0, const float* __restrict__ X1, const float* __restrict__ X2,
    const short* __restrict__ wpk0, const short* __restrict__ wpk1, const short* __restrict__ wpk2,
    const float* __restrict__ fb0, const float* __restrict__ fb1, const float* __restrict__ fb2,
    float* __restrict__ Y, short* __restrict__ Yb){
  int bid = blockIdx.x;
  int period = bid/27, r = bid - period*27;
  if(r<22){
    // ---- scatter: mids[g][pos] = (mid1, mid2) ----
    int s = period*22 + r; if(s>=TSC) return;
    int g = s/SCBLK; int e = (s - g*SCBLK)*256 + threadIdx.x;
    if(e>=NE) return;
    int i = g>>1;
    const int* row = mp + ((size_t)g*NE+e)*3;
    int dst = row[0]-i*NT;
    int pos = offs[g*(NT+1)+dst] + atomicAdd(&counts[g*NT+dst],1);
    mids[(size_t)g*NE+pos]=make_int2(row[1],row[2]);
    return;
  }
  // ---- fc transform: Y[rows,64] = X[rows,K] @ W + b (split-bf16 MFMA) ----
  int mID = period*5 + (r-22); if(mID>=TMM) return;
  int which = mID/532; int xb = mID - which*532;
  const float* X; const short* wpk; const float* b; int K;
  if(which==0){X=X0;wpk=wpk0;b=fb0;K=512;}
  else if(which==1){X=X1;wpk=wpk1;b=fb1;K=256;}
  else {X=X2;wpk=wpk2;b=fb2;K=128;}
  float* Yw = Y + (size_t)which*NT*64;
  short* Ybw = Yb + (size_t)which*NT*64;
  int wave = threadIdx.x>>6, lane = threadIdx.x&63;
  int row0 = xb*64 + wave*16;
  if(row0>=NT) return;
  int rr = row0 + (lane&15);
  int rc = min(rr, NT-1);
  const float* xr = X + (size_t)rc*K + ((lane>>4)<<3);
  int nk = K>>5;
  const short8* wh = (const short8*)wpk;
  const short8* wl = wh + (size_t)nk*256;
  f32x4 acc[4];
  #pragma unroll
  for(int c=0;c<4;c++) acc[c]=(f32x4){0.f,0.f,0.f,0.f};
  for(int kt=0;kt<nk;kt++){
    float4 f0=*(const float4*)(xr + kt*32);
    float4 f1=*(const float4*)(xr + kt*32 + 4);
    float xs[8]={f0.x,f0.y,f0.z,f0.w,f1.x,f1.y,f1.z,f1.w};
    short8 ah, al;
    #pragma unroll
    for(int j=0;j<8;j++){
      short h=f2bf(xs[j]); ah[j]=h;
      al[j]=f2bf(xs[j]-bf2f(h));
    }
    const short8* whk = wh + (size_t)kt*256 + lane;
    const short8* wlk = wl + (size_t)kt*256 + lane;
    #pragma unroll
    for(int c=0;c<4;c++){
      short8 bh = whk[c*64];
      short8 bl = wlk[c*64];
      acc[c]=__builtin_amdgcn_mfma_f32_16x16x32_bf16(ah,bh,acc[c],0,0,0);
      acc[c]=__builtin_amdgcn_mfma_f32_16x16x32_bf16(al,bh,acc[c],0,0,0);
      acc[c]=__builtin_amdgcn_mfma_f32_16x16x32_bf16(ah,bl,acc[c],0,0,0);
    }
  }
  int rbase = row0 + ((lane>>4)<<2);
  int colb = lane&15;
  #pragma unroll
  for(int c=0;c<4;c++){
    int col = c*16+colb;
    float bb = b[col];
    #pragma unroll
    for(int q=0;q<4;q++){
      int rw = rbase+q;
      if(rw<NT){
        float v = acc[c][q]+bb;
        Yw[(size_t)rw*64+col]=v;
        Ybw[(size_t)rw*64+col]=f2bf(v);
      }
    }
  }
}

// -------- X = beta0*Xa + beta1*Xb where Xa/Xb are bf16 st (layer 0), K=512 ---------
__global__ __launch_bounds__(256) void k_mm64fB(const short* __restrict__ Xa, const short* __restrict__ Xb,
               const float* __restrict__ accv_s, const float* __restrict__ q,
               const short* __restrict__ wpk,
               const float* __restrict__ b, float* __restrict__ Y, int rows, int act){
  const int K=512, nk=16;
  float b0, b1;
  compute_beta(accv_s, q, &b0, &b1);
  int wave = threadIdx.x>>6, lane = threadIdx.x&63;
  int row0 = blockIdx.x*64 + wave*16;
  if(row0>=rows) return;
  int r = row0 + (lane&15);
  int rc = min(r, rows-1);
  const short* xra = Xa + (size_t)rc*K + ((lane>>4)<<3);
  const short* xrb = Xb + (size_t)rc*K + ((lane>>4)<<3);
  const short8* wh = (const short8*)wpk;
  const short8* wl = wh + (size_t)nk*256;
  f32x4 acc[4];
  #pragma unroll
  for(int c=0;c<4;c++) acc[c]=(f32x4){0.f,0.f,0.f,0.f};
  for(int kt=0;kt<nk;kt++){
    short8 sa = *(const short8*)(xra + kt*32);
    short8 sb = *(const short8*)(xrb + kt*32);
    short8 ah, al;
    #pragma unroll
    for(int j=0;j<8;j++){
      float x = b0*bf2f(sa[j]) + b1*bf2f(sb[j]);
      short h=f2bf(x); ah[j]=h;
      al[j]=f2bf(x-bf2f(h));
    }
    const short8* whk = wh + (size_t)kt*256 + lane;
    const short8* wlk = wl + (size_t)kt*256 + lane;
    #pragma unroll
    for(int c=0;c<4;c++){
      short8 bh = whk[c*64];
      short8 bl = wlk[c*64];
      acc[c]=__builtin_amdgcn_mfma_f32_16x16x32_bf16(ah,bh,acc[c],0,0,0);
      acc[c]=__builtin_amdgcn_mfma_f32_16x16x32_bf16(al,bh,acc[c],0,0,0);
      acc[c]=__builtin_amdgcn_mfma_f32_16x16x32_bf16(ah,bl,acc[c],0,0,0);
    }
  }
  int rbase = row0 + ((lane>>4)<<2);
  int colb = lane&15;
  #pragma unroll
  for(int c=0;c<4;c++){
    int col = c*16+colb;
    float bb = b[col];
    #pragma unroll
    for(int q=0;q<4;q++){
      int rw = rbase+q;
      if(rw<rows){
        float v = acc[c][q]+bb;
        if(act) v = v>0.f? v : (__expf(v)-1.f);
        Y[(size_t)rw*64+col]=v;
      }
    }
  }
}

// -------- per-node attention projections: ptab[g][node][0..7]=h·a1, [8..15]=h·a2 ----
// optionally also writes the bf16 shadow of h (row already in registers) -> kills k_cvt
__global__ __launch_bounds__(256) void k_pre(const float* __restrict__ h, const float* __restrict__ a1,
              const float* __restrict__ a2, float* __restrict__ ptab, int ngroups,
              short* __restrict__ hbout){
  int node = blockIdx.x*256+threadIdx.x;
  if(node>=NN) return;
  const float* hr = h + (size_t)node*64;
  float4 hv[16];
  #pragma unroll
  for(int q=0;q<16;q++) hv[q]=((const float4*)hr)[q];
  if(hbout){
    short* hp = hbout + (size_t)node*64;
    #pragma unroll
    for(int qq=0;qq<8;qq++){
      float4 a=hv[2*qq], b4=hv[2*qq+1];
      short8 v;
      v[0]=f2bf(a.x); v[1]=f2bf(a.y); v[2]=f2bf(a.z); v[3]=f2bf(a.w);
      v[4]=f2bf(b4.x); v[5]=f2bf(b4.y); v[6]=f2bf(b4.z); v[7]=f2bf(b4.w);
      ((short8*)hp)[qq]=v;
    }
  }
  for(int g=0; g<ngroups; g++){
    const float* A1 = a1 + (size_t)g*512;
    const float* A2 = a2 + (size_t)g*512;
    float out[16];
    #pragma unroll
    for(int o=0;o<8;o++){
      float acc=0.f;
      #pragma unroll
      for(int q=0;q<16;q++){
        float4 w=((const float4*)A1)[o*16+q];
        acc += hv[q].x*w.x+hv[q].y*w.y+hv[q].z*w.z+hv[q].w*w.w;
      }
      out[o]=acc;
    }
    #pragma unroll
    for(int o=0;o<8;o++){
      float acc=0.f;
      #pragma unroll
      for(int q=0;q<16;q++){
        float4 w=((const float4*)A2)[o*16+q];
        acc += hv[q].x*w.x+hv[q].y*w.y+hv[q].z*w.z+hv[q].w*w.w;
      }
      out[8+o]=acc;
    }
    float* dp = ptab + ((size_t)g*NN+node)*16;
    #pragma unroll
    for(int q=0;q<4;q++)
      ((float4*)dp)[q]=make_float4(out[q*4],out[q*4+1],out[q*4+2],out[q*4+3]);
  }
}

// -------- fused edge-logit + segment softmax + accumulate + elu --------------------
// Pass B2a now preloads the chunk's 8 edges with UNIFORM guards (k<cnt wave-uniform):
// 8 broadcast mids loads + 16 bf16 gathers all in flight concurrently (vs serial
// one-at-a-time), then register-only LDS-alpha fma block. No launch-bounds cap
// (r2's spill) and no bpermute alphas (r2's pressure) -> expect ~44 VGPR, no spill.
__global__ __launch_bounds__(256) void k_seg(const int* __restrict__ offs_all, const float* __restrict__ ptab,
   const int2* __restrict__ mids_all, const float* __restrict__ h, const short* __restrict__ hb,
   short* __restrict__ stb, float* __restrict__ stf, int type, int tobf){
  __shared__ float wsh[4][64];
  int wave = threadIdx.x>>6, lane = threadIdx.x&63;
  int n = blockIdx.x*4 + wave;
  if(n>=NT) return;
  int p = blockIdx.y; int g = type*2+p;
  const int* offs = offs_all + (size_t)g*(NT+1);
  const int2* mids_g = mids_all + (size_t)g*NE;
  const float* pt = ptab + (size_t)g*NN*16;
  const unsigned short* hbp = (const unsigned short*)hb;

  int off = offs[n], end = offs[n+1];
  const float third = 1.f/3.f;
  int j = lane>>3, hh = lane&7;

  // per-(lane) head base: base_h = pA[h] + pB[h]/3  (consecutive 4B loads across h)
  const float* pn = pt + (size_t)(type*NT+n)*16;
  float baseh = pn[hh] + pn[8+hh]*third;

  // ---- Pass A: per-lane online (m,den) over its own edges, then merge over j ----
  float m = -1e30f, den = 0.f;
  for(int s=off+j; s<end; s+=8){
    int2 mm = mids_g[s];
    float q1 = pt[(size_t)mm.x*16 + 8 + hh];
    float q2 = pt[(size_t)mm.y*16 + 8 + hh];
    float e = baseh + (q1+q2)*third;
    float ev = e>0.f? e : 0.2f*e;
    float mn = fmaxf(m, ev);
    den = den*__expf(m-mn) + __expf(ev-mn);
    m = mn;
  }
  #pragma unroll
  for(int o8=8;o8<=32;o8<<=1){
    float om = __shfl_xor(m, o8, 64);
    float od = __shfl_xor(den, o8, 64);
    float mn = fmaxf(m, om);
    den = den*__expf(m-mn) + od*__expf(om-mn);
    m = mn;
  }
  float invD = 1.f/fmaxf(den, 1e-9f);    // (M,D) now uniform per head across j

  // ---- Pass B: chunks of 8 edges ----
  float o[8]={0.f,0.f,0.f,0.f,0.f,0.f,0.f,0.f};
  for(int base=off; base<end; base+=8){
    int cnt = end-base; if(cnt>8) cnt=8;  // wave-uniform
    // B1 (parallel): w for 8 edges x 8 heads, one expf
    int s = base+j;
    float w = 0.f;
    if(s<end){
      int2 mm = mids_g[s];
      float q1 = pt[(size_t)mm.x*16 + 8 + hh];
      float q2 = pt[(size_t)mm.y*16 + 8 + hh];
      float e = baseh + (q1+q2)*third;
      float ev = e>0.f? e : 0.2f*e;
      w = __expf(ev-m)*invD;
    }
    wsh[wave][lane] = w;                  // wave-private broadcast row
    // B2a: preload live edges' summed mid features; uniform guards -> whole-wave
    // skip on tails; all surviving loads issue back-to-back (16 gathers in flight)
    float hvm[8];
    #pragma unroll
    for(int k=0;k<8;k++){
      if(k<cnt){
        int2 mm = mids_g[base+k];         // uniform broadcast load
        unsigned ux = hbp[(size_t)mm.x*64+lane];
        unsigned uy = hbp[(size_t)mm.y*64+lane];
        hvm[k] = __uint_as_float(ux<<16) + __uint_as_float(uy<<16);
      }
    }
    // B2b: register-only LDS-alpha fma
    #pragma unroll
    for(int k=0;k<8;k++){
      if(k<cnt){
        float4 a0 = *(const float4*)&wsh[wave][k*8];
        float4 a1 = *(const float4*)&wsh[wave][k*8+4];
        o[0]+=a0.x*hvm[k]; o[1]+=a0.y*hvm[k]; o[2]+=a0.z*hvm[k]; o[3]+=a0.w*hvm[k];
        o[4]+=a1.x*hvm[k]; o[5]+=a1.y*hvm[k]; o[6]+=a1.z*hvm[k]; o[7]+=a1.w*hvm[k];
      }
    }
  }

  float hn = h[((size_t)type*NT+(size_t)n)*64+lane];
  short* stbp = stb + (size_t)p*NT*512 + (size_t)n*512 + lane;
  float* stfp = stf + (size_t)p*NT*512 + (size_t)n*512 + lane;
  #pragma unroll
  for(int q=0;q<8;q++){
    float v = (end>off)? (o[q] + hn)*third : 0.f;
    v = v>0.f? v : (__expf(v)-1.f);
    if(tobf) stbp[q*64] = f2bf(v);
    else     stfp[q*64] = v;
  }
}

// -------- bf16 MFMA, B direct from L2: accv_s[p][col] += sum_n tanh(st@W + b) ------
// Hierarchical reduction epilogue: per-wave butterfly -> LDS red[4][128] -> one
// atomicAdd per block per column.
__global__ __launch_bounds__(256) void k_tanhmm(const short* __restrict__ stb, const float* __restrict__ stf,
                        int isbf, const short* __restrict__ bpk,
                        const float* __restrict__ bias, float* __restrict__ accv_s){
  __shared__ float red[4][128];
  int wave=threadIdx.x>>6, lane=threadIdx.x&63;
  int p=blockIdx.y;
  int row0 = (blockIdx.x*4+wave)*16;
  int active = (row0<NT);
  int rA = row0 + (lane&15); if(rA>NT-1) rA=NT-1;
  const short* arowb = stb + (size_t)p*NT*512 + (size_t)rA*512 + ((lane>>4)<<3);
  const float* arowf = stf + (size_t)p*NT*512 + (size_t)rA*512 + ((lane>>4)<<3);
  f32x4 acc[8];
  #pragma unroll
  for(int c=0;c<8;c++) acc[c]=(f32x4){0.f,0.f,0.f,0.f};
  const short8* bp = (const short8*)bpk;
  if(active){
    for(int kt=0;kt<16;kt++){
      short8 a;
      if(isbf){
        a = *(const short8*)(arowb + kt*32);
      } else {
        float4 f0 = *(const float4*)(arowf + kt*32);
        float4 f1 = *(const float4*)(arowf + kt*32 + 4);
        a[0]=f2bf(f0.x); a[1]=f2bf(f0.y); a[2]=f2bf(f0.z); a[3]=f2bf(f0.w);
        a[4]=f2bf(f1.x); a[5]=f2bf(f1.y); a[6]=f2bf(f1.z); a[7]=f2bf(f1.w);
      }
      const short8* bk = bp + (size_t)kt*512 + lane;
      #pragma unroll
      for(int c=0;c<8;c++){
        short8 bfr = bk[c*64];              // coalesced 1KB/wave, L2-hit
        acc[c]=__builtin_amdgcn_mfma_f32_16x16x32_bf16(a,bfr,acc[c],0,0,0);
      }
    }
  }
  int rbase = row0 + ((lane>>4)<<2);
  int colb = lane&15;
  float sc[8];
  #pragma unroll
  for(int c=0;c<8;c++){
    float s=0.f;
    if(active){
      float bb=bias[c*16+colb];
      #pragma unroll
      for(int r=0;r<4;r++){
        if(rbase+r<NT) s += fast_tanh(acc[c][r]+bb);
      }
    }
    s += __shfl_xor(s,16,64);
    s += __shfl_xor(s,32,64);
    sc[c]=s;
  }
  if(lane<16){
    #pragma unroll
    for(int c=0;c<8;c++) red[wave][c*16+lane]=sc[c];
  }
  __syncthreads();
  if(threadIdx.x<128){
    float t = red[0][threadIdx.x]+red[1][threadIdx.x]+red[2][threadIdx.x]+red[3][threadIdx.x];
    atomicAdd(&accv_s[p*128+threadIdx.x], t);
  }
}

// -------- final: logits[t] = (b0*st0[row]+b1*st1[row]) @ lW1 + lb1 -----------------
__global__ __launch_bounds__(64) void k_final(const float* __restrict__ st0, const float* __restrict__ st1,
      const float* __restrict__ accv_s, const float* __restrict__ q,
      const float* __restrict__ lW1, const float* __restrict__ lb1,
      const int* __restrict__ tgt, float* __restrict__ out){
  int t=blockIdx.x; int lane=threadIdx.x;
  int row=tgt[t];
  float b0, b1;
  compute_beta(accv_s, q, &b0, &b1);
  float acc[8]={0.f,0.f,0.f,0.f,0.f,0.f,0.f,0.f};
  #pragma unroll
  for(int kk=0;kk<8;kk++){
    int k=kk*64+lane;
    float hm=b0*st0[(size_t)row*512+k]+b1*st1[(size_t)row*512+k];
    const float4* wp=(const float4*)(lW1+(size_t)k*8);
    float4 w0=wp[0], w1=wp[1];
    acc[0]+=hm*w0.x; acc[1]+=hm*w0.y; acc[2]+=hm*w0.z; acc[3]+=hm*w0.w;
    acc[4]+=hm*w1.x; acc[5]+=hm*w1.y; acc[6]+=hm*w1.z; acc[7]+=hm*w1.w;
  }
  #pragma unroll
  for(int c=0;c<8;c++){
    #pragma unroll
    for(int off=32;off>0;off>>=1) acc[c]+=__shfl_xor(acc[c],off,64);
  }
  if(lane<8){
    float v=0.f;
    #pragma unroll
    for(int c=0;c<8;c++) if(lane==c) v=acc[c];
    out[t*8+lane]=v+lb1[lane];
  }
}

extern "C" void kernel_launch(void* const* d_in, const int* in_sizes, int n_in,
                              void* d_out, int out_size, void* d_ws, size_t ws_size,
                              hipStream_t stream) {
  const float* X0=(const float*)d_in[0];
  const float* X1=(const float*)d_in[1];
  const float* X2=(const float*)d_in[2];
  const float* fcW0=(const float*)d_in[3]; const float* fcb0=(const float*)d_in[4];
  const float* fcW1=(const float*)d_in[5]; const float* fcb1=(const float*)d_in[6];
  const float* fcW2=(const float*)d_in[7]; const float* fcb2=(const float*)d_in[8];
  const float* attn1=(const float*)d_in[9];
  const float* attn2=(const float*)d_in[10];
  const float* mpW=(const float*)d_in[11];
  const float* mpb=(const float*)d_in[12];
  const float* mpq=(const float*)d_in[13];
  const float* lW0=(const float*)d_in[14]; const float* lb0=(const float*)d_in[15];
  const float* lW1=(const float*)d_in[16]; const float* lb1=(const float*)d_in[17];
  const int* mp=(const int*)d_in[18];
  const int* tgt=(const int*)d_in[19];
  float* out=(float*)d_out;

  // workspace layout (total ~273.6 MB). Liveness-checked carve-outs:
  char* ws=(char*)d_ws;
  float* h0   =(float*)(ws+0);              // N*64 f32      (live from k_scmm on)
  float* h1   =(float*)(ws+26112000);       // N*64 f32
  float* ptab =(float*)(ws+52224000);       // 6*N*16 f32
  int*   offs =(int*  )(ws+91392000);       // 6*(NT+1)
  int*   counts=(int* )(ws+92208128);       // 6*NT (live through k_scmm scatter part)
  int2*  mids =(int2* )(ws+100224128);      // 6*E int2 = 14.4 MB
  short* hb   =(short*)(ws+114624128);      // N*64 bf16 = 13.056 MB
  // packed fc weights AFTER hb (counts must stay live past packWall for k_scmm)
  short* wpk0 =(short*)(ws+127680128);      // +128KB  K=512
  short* wpk1 =(short*)(ws+127811200);      // +64KB   K=256
  short* wpkL =(short*)(ws+127876736);      // +128KB  K=512
  short* wpk2 =(short*)(ws+128007808);      // +32KB   K=128
  // st region: bf16 st (layer 0) / f32 st (layer 1) share (sequential liveness)
  short* stb  =(short*)(ws+133824128);      // 2*NT*512 bf16 (layer 0)
  float* stf  =(float*)(ws+133824128);      // 2*NT*512 f32  (layer 1)
  short* bpk4 =(short*)(ws+273088128);      // 4 packed mpW mats, 512 KB
  float* accv =(float*)(ws+273612416);      // 4 slots x 256 f32
  // bsum: used ONLY during CSR build; placed in st region (first written by k_seg later)
  int*   bsum =(int*  )(ws+133824128);      // 6*NBLK ints = 3192 B

  dim3 b256(256);
  // CSR build prefix (mp_idx is layer-invariant; built once per launch)
  k_zero<<<dim3((6*NT+255)/256),b256,0,stream>>>(counts,6*NT);
  k_hist<<<dim3((NE+255)/256,6),b256,0,stream>>>(mp,counts);
  k_blkred<<<dim3(NBLK,6),b256,0,stream>>>(counts,bsum);
  k_scansums<<<dim3(6),b256,0,stream>>>(bsum);
  k_scanapply<<<dim3(NBLK,6),b256,0,stream>>>(counts,bsum,offs);

  // pack fc weights + all 4 mpW mats + zero accv
  k_packWall<<<dim3(32,8),b256,0,stream>>>(fcW0,fcW1,fcW2,lW0,mpW,wpk0,wpk1,wpk2,wpkL,bpk4,accv);

  // FUSED: edge scatter + per-type feature transforms (h0 f32 + hb bf16 shadow)
  k_scmm<<<dim3(320*27),b256,0,stream>>>(mp,offs,counts,mids,X0,X1,X2,
                                         wpk0,wpk1,wpk2,fcb0,fcb1,fcb2,h0,hb);

  // ---- layer 0 (st in bf16) ----
  k_pre<<<dim3((NN+255)/256),b256,0,stream>>>(h0,attn1,attn2,ptab,6,(short*)nullptr);
  for(int type=0;type<3;type++){
    k_seg<<<dim3(NT/4,2),b256,0,stream>>>(offs,ptab,mids,h0,hb,stb,stf,type,1);
    k_tanhmm<<<dim3(532,2),b256,0,stream>>>(stb,stf,1,bpk4+(size_t)type*65536,
                                            mpb+(0*3+type)*128,accv+type*256);
    k_mm64fB<<<dim3(532),b256,0,stream>>>(stb,stb+(size_t)NT*512,accv+type*256,mpq+(0*3+type)*128,
                                          wpkL,lb0,h1+(size_t)type*NT*64,NT,1);
  }

  // ---- layer 1 (st in f32; only type 0 reaches the output) ----
  // k_pre also writes hb = bf16(h1) (row already in registers) -> k_cvt eliminated
  k_pre<<<dim3((NN+255)/256),b256,0,stream>>>(h1,attn1+(size_t)6*512,attn2+(size_t)6*512,ptab,2,hb);
  k_seg<<<dim3(NT/4,2),b256,0,stream>>>(offs,ptab,mids,h1,hb,stb,stf,0,0);
  k_tanhmm<<<dim3(532,2),b256,0,stream>>>(stb,stf,0,bpk4+(size_t)3*65536,
                                          mpb+(1*3+0)*128,accv+3*256);
  k_final<<<dim3(NTGT),dim3(64),0,stream>>>(stf,stf+(size_t)NT*512,accv+3*256,mpq+(1*3+0)*128,
                                            lW1,lb1,tgt,out);
}

// Round 11
// 1123.702 us; speedup vs baseline: 1.0937x; 1.0937x over previous
//
#include <hip/hip_runtime.h>
#include <hip/hip_bf16.h>
#include <math.h>

#define NT 34000
#define NTYPES 3
#define NMP 2
#define NE 300000
#define HH 8
#define DD 64
#define HD 512
#define AV 128
#define NCLS 8
#define NTGT 1000
#define NN (NTYPES*NT)
#define NBLK 133   // ceil(NT/256)
#define SCBLK 1172 // ceil(NE/256)
#define TSC (6*SCBLK)   // 7032 scatter blocks
#define TMM (3*532)     // 1596 mm64f blocks
#define MAXC 8     // ev-stash chunks (64 edges); fallback recompute beyond

typedef short short8 __attribute__((ext_vector_type(8)));
typedef float f32x4 __attribute__((ext_vector_type(4)));

__device__ __forceinline__ short f2bf(float f){
  unsigned u = __float_as_uint(f);
  unsigned r = u + 0x7FFFu + ((u>>16)&1u);
  return (short)(r>>16);
}
__device__ __forceinline__ float bf2f(short s){
  return __uint_as_float(((unsigned)(unsigned short)s)<<16);
}
__device__ __forceinline__ float fast_tanh(float x){
  x = fminf(15.f, fmaxf(-15.f, x));
  float t = __expf(2.f*x);
  return (t-1.f)/(t+1.f);
}

// beta = softmax over P of (mean tanh)·q, computed redundantly per-thread from accv slot
__device__ __forceinline__ void compute_beta(const float* __restrict__ av,
                                             const float* __restrict__ q,
                                             float* b0, float* b1){
  float s0=0.f, s1=0.f;
  #pragma unroll
  for(int c=0;c<32;c++){
    float4 a0=((const float4*)av)[c];
    float4 a1=((const float4*)(av+128))[c];
    float4 qq=((const float4*)q)[c];
    s0 += a0.x*qq.x+a0.y*qq.y+a0.z*qq.z+a0.w*qq.w;
    s1 += a1.x*qq.x+a1.y*qq.y+a1.z*qq.z+a1.w*qq.w;
  }
  s0 /= (float)NT; s1 /= (float)NT;
  float mm=fmaxf(s0,s1);
  float e0=__expf(s0-mm), e1=__expf(s1-mm);
  float d=e0+e1;
  *b0=e0/d; *b1=e1/d;
}

// ---------------- CSR build ----------------
__global__ void k_zero(int* __restrict__ p, int n){
  int i = blockIdx.x*256+threadIdx.x; if(i<n) p[i]=0;
}

__global__ void k_hist(const int* __restrict__ mp, int* __restrict__ counts){
  int e = blockIdx.x*256+threadIdx.x; int g = blockIdx.y;
  if(e>=NE) return;
  int i = g>>1;
  int dst = mp[((size_t)g*NE+e)*3] - i*NT;
  atomicAdd(&counts[g*NT+dst],1);
}

// block-level reduce: bsum[g][blk] = sum of counts[g][blk*256 .. +255]
__global__ __launch_bounds__(256) void k_blkred(const int* __restrict__ counts, int* __restrict__ bsum){
  int g=blockIdx.y, blk=blockIdx.x, t=threadIdx.x;
  int idx=blk*256+t;
  int v=(idx<NT)? counts[g*NT+idx]:0;
  #pragma unroll
  for(int off=32;off;off>>=1) v+=__shfl_down(v,off,64);
  __shared__ int sh[4];
  if((t&63)==0) sh[t>>6]=v;
  __syncthreads();
  if(t==0) bsum[g*NBLK+blk]=sh[0]+sh[1]+sh[2]+sh[3];
}

// exclusive scan of the 133 block sums per group (in place)
__global__ __launch_bounds__(256) void k_scansums(int* __restrict__ bsum){
  int g=blockIdx.x; int t=threadIdx.x;
  __shared__ int s[256];
  int v=(t<NBLK)? bsum[g*NBLK+t]:0;
  s[t]=v; __syncthreads();
  for(int off=1;off<256;off<<=1){
    int tmp=(t>=off)?s[t-off]:0; __syncthreads();
    s[t]+=tmp; __syncthreads();
  }
  if(t<NBLK) bsum[g*NBLK+t]=s[t]-v;
}

// rescan each chunk, add block prefix, write offs, zero counts for scatter reuse
__global__ __launch_bounds__(256) void k_scanapply(int* __restrict__ counts, const int* __restrict__ bsum,
                                                   int* __restrict__ offs){
  int g=blockIdx.y, blk=blockIdx.x, t=threadIdx.x;
  int idx=blk*256+t;
  int v=(idx<NT)? counts[g*NT+idx]:0;
  __shared__ int s[256];
  s[t]=v; __syncthreads();
  for(int off=1;off<256;off<<=1){
    int tmp=(t>=off)?s[t-off]:0; __syncthreads();
    s[t]+=tmp; __syncthreads();
  }
  int excl = s[t]-v + bsum[g*NBLK+blk];
  if(idx<NT){ offs[g*(NT+1)+idx]=excl; counts[g*NT+idx]=0; }
  if(idx==NT-1) offs[g*(NT+1)+NT]=excl+v;
}

// -------- pack fc weights (hi/lo split-bf16) + all 4 mpW mats (bf16) + zero accv ----
__global__ void k_packWall(const float* __restrict__ W0, const float* __restrict__ W1,
                           const float* __restrict__ W2, const float* __restrict__ WL,
                           const float* __restrict__ mpW,
                           short* __restrict__ p0, short* __restrict__ p1,
                           short* __restrict__ p2, short* __restrict__ pL,
                           short* __restrict__ bpk4, float* __restrict__ accv){
  int which = blockIdx.y;
  int tid = blockIdx.x*256+threadIdx.x;
  if(which<4){
    const float* W; short* wpk; int K;
    if(which==0){W=W0;wpk=p0;K=512;}
    else if(which==1){W=W1;wpk=p1;K=256;}
    else if(which==2){W=W2;wpk=p2;K=128;}
    else {W=WL;wpk=pL;K=512;}
    int nk = K>>5;
    int total = nk*256;
    if(tid>=total) return;
    int lane = tid&63; int c=(tid>>6)&3; int kt=tid>>8;
    int col = c*16 + (lane&15);
    int kbase = kt*32 + ((lane>>4)<<3);
    short8 hi, lo;
    #pragma unroll
    for(int j=0;j<8;j++){
      float w = W[(size_t)(kbase+j)*64+col];
      short h = f2bf(w); hi[j]=h;
      lo[j] = f2bf(w - bf2f(h));
    }
    ((short8*)wpk)[tid] = hi;
    ((short8*)wpk)[total+tid] = lo;
  } else {
    if(which==4 && tid<1024) accv[tid]=0.f;   // zero all 4 accv slots
    if(tid>=8192) return;
    // mpW slots used: (l,t) = (0,0),(0,1),(0,2),(1,0) -> flat 0,1,2,3 == which-4
    const float* W = mpW + (size_t)(which-4)*512*128;
    short* out = bpk4 + (size_t)(which-4)*65536;
    int lane=tid&63; int c=(tid>>6)&7; int t=tid>>9;
    int kbase = t*32 + ((lane>>4)<<3);
    int col = c*16 + (lane&15);
    short8 v;
    #pragma unroll
    for(int jj=0;jj<8;jj++) v[jj]=f2bf(W[(size_t)(kbase+jj)*128+col]);
    ((short8*)out)[tid]=v;
  }
}

// -------- FUSED: edge scatter (latency-bound) + per-type fc MFMA (compute-bound) ----
// Interleaved flat grid (period 27 = 22 scatter + 5 mm) so both populations are
// co-resident per CU and hide each other.
__global__ __launch_bounds__(256) void k_scmm(const int* __restrict__ mp, const int* __restrict__ offs,
    int* __restrict__ counts, int2* __restrict__ mids,
    const float* __restrict__ X0, const float* __restrict__ X1, const float* __restrict__ X2,
    const short* __restrict__ wpk0, const short* __restrict__ wpk1, const short* __restrict__ wpk2,
    const float* __restrict__ fb0, const float* __restrict__ fb1, const float* __restrict__ fb2,
    float* __restrict__ Y, short* __restrict__ Yb){
  int bid = blockIdx.x;
  int period = bid/27, r = bid - period*27;
  if(r<22){
    // ---- scatter: mids[g][pos] = (mid1, mid2) ----
    int s = period*22 + r; if(s>=TSC) return;
    int g = s/SCBLK; int e = (s - g*SCBLK)*256 + threadIdx.x;
    if(e>=NE) return;
    int i = g>>1;
    const int* row = mp + ((size_t)g*NE+e)*3;
    int dst = row[0]-i*NT;
    int pos = offs[g*(NT+1)+dst] + atomicAdd(&counts[g*NT+dst],1);
    mids[(size_t)g*NE+pos]=make_int2(row[1],row[2]);
    return;
  }
  // ---- fc transform: Y[rows,64] = X[rows,K] @ W + b (split-bf16 MFMA) ----
  int mID = period*5 + (r-22); if(mID>=TMM) return;
  int which = mID/532; int xb = mID - which*532;
  const float* X; const short* wpk; const float* b; int K;
  if(which==0){X=X0;wpk=wpk0;b=fb0;K=512;}
  else if(which==1){X=X1;wpk=wpk1;b=fb1;K=256;}
  else {X=X2;wpk=wpk2;b=fb2;K=128;}
  float* Yw = Y + (size_t)which*NT*64;
  short* Ybw = Yb + (size_t)which*NT*64;
  int wave = threadIdx.x>>6, lane = threadIdx.x&63;
  int row0 = xb*64 + wave*16;
  if(row0>=NT) return;
  int rr = row0 + (lane&15);
  int rc = min(rr, NT-1);
  const float* xr = X + (size_t)rc*K + ((lane>>4)<<3);
  int nk = K>>5;
  const short8* wh = (const short8*)wpk;
  const short8* wl = wh + (size_t)nk*256;
  f32x4 acc[4];
  #pragma unroll
  for(int c=0;c<4;c++) acc[c]=(f32x4){0.f,0.f,0.f,0.f};
  for(int kt=0;kt<nk;kt++){
    float4 f0=*(const float4*)(xr + kt*32);
    float4 f1=*(const float4*)(xr + kt*32 + 4);
    float xs[8]={f0.x,f0.y,f0.z,f0.w,f1.x,f1.y,f1.z,f1.w};
    short8 ah, al;
    #pragma unroll
    for(int j=0;j<8;j++){
      short h=f2bf(xs[j]); ah[j]=h;
      al[j]=f2bf(xs[j]-bf2f(h));
    }
    const short8* whk = wh + (size_t)kt*256 + lane;
    const short8* wlk = wl + (size_t)kt*256 + lane;
    #pragma unroll
    for(int c=0;c<4;c++){
      short8 bh = whk[c*64];
      short8 bl = wlk[c*64];
      acc[c]=__builtin_amdgcn_mfma_f32_16x16x32_bf16(ah,bh,acc[c],0,0,0);
      acc[c]=__builtin_amdgcn_mfma_f32_16x16x32_bf16(al,bh,acc[c],0,0,0);
      acc[c]=__builtin_amdgcn_mfma_f32_16x16x32_bf16(ah,bl,acc[c],0,0,0);
    }
  }
  int rbase = row0 + ((lane>>4)<<2);
  int colb = lane&15;
  #pragma unroll
  for(int c=0;c<4;c++){
    int col = c*16+colb;
    float bb = b[col];
    #pragma unroll
    for(int q=0;q<4;q++){
      int rw = rbase+q;
      if(rw<NT){
        float v = acc[c][q]+bb;
        Yw[(size_t)rw*64+col]=v;
        Ybw[(size_t)rw*64+col]=f2bf(v);
      }
    }
  }
}

// -------- X = beta0*Xa + beta1*Xb where Xa/Xb are bf16 st (layer 0), K=512 ---------
__global__ __launch_bounds__(256) void k_mm64fB(const short* __restrict__ Xa, const short* __restrict__ Xb,
               const float* __restrict__ accv_s, const float* __restrict__ q,
               const short* __restrict__ wpk,
               const float* __restrict__ b, float* __restrict__ Y, int rows, int act){
  const int K=512, nk=16;
  float b0, b1;
  compute_beta(accv_s, q, &b0, &b1);
  int wave = threadIdx.x>>6, lane = threadIdx.x&63;
  int row0 = blockIdx.x*64 + wave*16;
  if(row0>=rows) return;
  int r = row0 + (lane&15);
  int rc = min(r, rows-1);
  const short* xra = Xa + (size_t)rc*K + ((lane>>4)<<3);
  const short* xrb = Xb + (size_t)rc*K + ((lane>>4)<<3);
  const short8* wh = (const short8*)wpk;
  const short8* wl = wh + (size_t)nk*256;
  f32x4 acc[4];
  #pragma unroll
  for(int c=0;c<4;c++) acc[c]=(f32x4){0.f,0.f,0.f,0.f};
  for(int kt=0;kt<nk;kt++){
    short8 sa = *(const short8*)(xra + kt*32);
    short8 sb = *(const short8*)(xrb + kt*32);
    short8 ah, al;
    #pragma unroll
    for(int j=0;j<8;j++){
      float x = b0*bf2f(sa[j]) + b1*bf2f(sb[j]);
      short h=f2bf(x); ah[j]=h;
      al[j]=f2bf(x-bf2f(h));
    }
    const short8* whk = wh + (size_t)kt*256 + lane;
    const short8* wlk = wl + (size_t)kt*256 + lane;
    #pragma unroll
    for(int c=0;c<4;c++){
      short8 bh = whk[c*64];
      short8 bl = wlk[c*64];
      acc[c]=__builtin_amdgcn_mfma_f32_16x16x32_bf16(ah,bh,acc[c],0,0,0);
      acc[c]=__builtin_amdgcn_mfma_f32_16x16x32_bf16(al,bh,acc[c],0,0,0);
      acc[c]=__builtin_amdgcn_mfma_f32_16x16x32_bf16(ah,bl,acc[c],0,0,0);
    }
  }
  int rbase = row0 + ((lane>>4)<<2);
  int colb = lane&15;
  #pragma unroll
  for(int c=0;c<4;c++){
    int col = c*16+colb;
    float bb = b[col];
    #pragma unroll
    for(int q=0;q<4;q++){
      int rw = rbase+q;
      if(rw<rows){
        float v = acc[c][q]+bb;
        if(act) v = v>0.f? v : (__expf(v)-1.f);
        Y[(size_t)rw*64+col]=v;
      }
    }
  }
}

// -------- per-node attention projections: ptab[g][node][0..7]=h·a1, [8..15]=h·a2 ----
// optionally also writes the bf16 shadow of h (row already in registers) -> kills k_cvt
__global__ __launch_bounds__(256) void k_pre(const float* __restrict__ h, const float* __restrict__ a1,
              const float* __restrict__ a2, float* __restrict__ ptab, int ngroups,
              short* __restrict__ hbout){
  int node = blockIdx.x*256+threadIdx.x;
  if(node>=NN) return;
  const float* hr = h + (size_t)node*64;
  float4 hv[16];
  #pragma unroll
  for(int q=0;q<16;q++) hv[q]=((const float4*)hr)[q];
  if(hbout){
    short* hp = hbout + (size_t)node*64;
    #pragma unroll
    for(int qq=0;qq<8;qq++){
      float4 a=hv[2*qq], b4=hv[2*qq+1];
      short8 v;
      v[0]=f2bf(a.x); v[1]=f2bf(a.y); v[2]=f2bf(a.z); v[3]=f2bf(a.w);
      v[4]=f2bf(b4.x); v[5]=f2bf(b4.y); v[6]=f2bf(b4.z); v[7]=f2bf(b4.w);
      ((short8*)hp)[qq]=v;
    }
  }
  for(int g=0; g<ngroups; g++){
    const float* A1 = a1 + (size_t)g*512;
    const float* A2 = a2 + (size_t)g*512;
    float out[16];
    #pragma unroll
    for(int o=0;o<8;o++){
      float acc=0.f;
      #pragma unroll
      for(int q=0;q<16;q++){
        float4 w=((const float4*)A1)[o*16+q];
        acc += hv[q].x*w.x+hv[q].y*w.y+hv[q].z*w.z+hv[q].w*w.w;
      }
      out[o]=acc;
    }
    #pragma unroll
    for(int o=0;o<8;o++){
      float acc=0.f;
      #pragma unroll
      for(int q=0;q<16;q++){
        float4 w=((const float4*)A2)[o*16+q];
        acc += hv[q].x*w.x+hv[q].y*w.y+hv[q].z*w.z+hv[q].w*w.w;
      }
      out[8+o]=acc;
    }
    float* dp = ptab + ((size_t)g*NN+node)*16;
    #pragma unroll
    for(int q=0;q<4;q++)
      ((float4*)dp)[q]=make_float4(out[q*4],out[q*4+1],out[q*4+2],out[q*4+3]);
  }
}

// -------- fused edge-logit + segment softmax + accumulate + elu --------------------
// B2 is SERIAL (r1/r2/r4/r10 all proved register-widening loses via occupancy).
// New: Pass A stashes ev in LDS (evw, 8KB, zero VGPR cost); B1's recompute chain
// (mids->ptab->ptab, ~400cy/chunk) becomes one ds_read + exp. Fallback recompute
// for segments >64 edges. Output st is bf16 (layer 0) or f32 (layer 1).
__global__ __launch_bounds__(256) void k_seg(const int* __restrict__ offs_all, const float* __restrict__ ptab,
   const int2* __restrict__ mids_all, const float* __restrict__ h, const short* __restrict__ hb,
   short* __restrict__ stb, float* __restrict__ stf, int type, int tobf){
  __shared__ float evw[4][MAXC][64];
  __shared__ float wsh[4][64];
  int wave = threadIdx.x>>6, lane = threadIdx.x&63;
  int n = blockIdx.x*4 + wave;
  if(n>=NT) return;
  int p = blockIdx.y; int g = type*2+p;
  const int* offs = offs_all + (size_t)g*(NT+1);
  const int2* mids_g = mids_all + (size_t)g*NE;
  const float* pt = ptab + (size_t)g*NN*16;
  const unsigned short* hbp = (const unsigned short*)hb;

  int off = offs[n], end = offs[n+1];
  int nc = (end-off+7)>>3;               // wave-uniform chunk count
  const float third = 1.f/3.f;
  int j = lane>>3, hh = lane&7;

  // per-(lane) head base: base_h = pA[h] + pB[h]/3  (consecutive 4B loads across h)
  const float* pn = pt + (size_t)(type*NT+n)*16;
  float baseh = pn[hh] + pn[8+hh]*third;

  // ---- Pass A: compute ev once, stash to LDS, online (m,den) ----
  float m = -1e30f, den = 0.f;
  for(int c=0;c<nc;c++){
    int s = off + c*8 + j;
    float ev = -1e30f;
    if(s<end){
      int2 mm = mids_g[s];
      float q1 = pt[(size_t)mm.x*16 + 8 + hh];
      float q2 = pt[(size_t)mm.y*16 + 8 + hh];
      float e = baseh + (q1+q2)*third;
      ev = e>0.f? e : 0.2f*e;
      float mn = fmaxf(m, ev);
      den = den*__expf(m-mn) + __expf(ev-mn);
      m = mn;
    }
    if(c<MAXC) evw[wave][c][lane]=ev;    // uniform branch; dead lanes stash -1e30
  }
  // merge (m,den) across j (8 edge-slots), hh invariant
  #pragma unroll
  for(int o8=8;o8<=32;o8<<=1){
    float om = __shfl_xor(m, o8, 64);
    float od = __shfl_xor(den, o8, 64);
    float mn = fmaxf(m, om);
    den = den*__expf(m-mn) + od*__expf(om-mn);
    m = mn;
  }
  float invD = 1.f/fmaxf(den, 1e-9f);    // (M,D) now uniform per head across j

  // ---- Pass B: chunks of 8 edges ----
  float o[8]={0.f,0.f,0.f,0.f,0.f,0.f,0.f,0.f};
  int c = 0;
  for(int base=off; base<end; base+=8, c++){
    // B1: w from the LDS ev-stash (one ds_read + exp; no global reloads)
    float w;
    if(c<MAXC){                          // uniform
      float ev = evw[wave][c][lane];
      w = __expf(ev-m)*invD;             // ev=-1e30 -> w=0 for dead lanes
    } else {
      // fallback (segments >64 edges): recompute old-style
      int s = base+j; w = 0.f;
      if(s<end){
        int2 mm = mids_g[s];
        float q1 = pt[(size_t)mm.x*16 + 8 + hh];
        float q2 = pt[(size_t)mm.y*16 + 8 + hh];
        float e = baseh + (q1+q2)*third;
        float ev2 = e>0.f? e : 0.2f*e;
        w = __expf(ev2-m)*invD;
      }
    }
    wsh[wave][lane] = w;                  // wave-private broadcast row
    // B2 (serial over the chunk's edges): bf16 gathers + LDS b128 alpha + fma
    int cnt = min(8, end-base);
    for(int k=0;k<cnt;k++){
      int2 mm = mids_g[base+k];
      unsigned ux = hbp[(size_t)mm.x*64+lane];
      unsigned uy = hbp[(size_t)mm.y*64+lane];
      float hvm = __uint_as_float(ux<<16) + __uint_as_float(uy<<16);
      float4 a0 = *(const float4*)&wsh[wave][k*8];
      float4 a1 = *(const float4*)&wsh[wave][k*8+4];
      o[0]+=a0.x*hvm; o[1]+=a0.y*hvm; o[2]+=a0.z*hvm; o[3]+=a0.w*hvm;
      o[4]+=a1.x*hvm; o[5]+=a1.y*hvm; o[6]+=a1.z*hvm; o[7]+=a1.w*hvm;
    }
  }

  float hn = h[((size_t)type*NT+(size_t)n)*64+lane];
  short* stbp = stb + (size_t)p*NT*512 + (size_t)n*512 + lane;
  float* stfp = stf + (size_t)p*NT*512 + (size_t)n*512 + lane;
  #pragma unroll
  for(int q=0;q<8;q++){
    float v = (end>off)? (o[q] + hn)*third : 0.f;
    v = v>0.f? v : (__expf(v)-1.f);
    if(tobf) stbp[q*64] = f2bf(v);
    else     stfp[q*64] = v;
  }
}

// -------- bf16 MFMA, B direct from L2: accv_s[p][col] += sum_n tanh(st@W + b) ------
// Hierarchical reduction epilogue: per-wave butterfly -> LDS red[4][128] -> one
// atomicAdd per block per column.
__global__ __launch_bounds__(256) void k_tanhmm(const short* __restrict__ stb, const float* __restrict__ stf,
                        int isbf, const short* __restrict__ bpk,
                        const float* __restrict__ bias, float* __restrict__ accv_s){
  __shared__ float red[4][128];
  int wave=threadIdx.x>>6, lane=threadIdx.x&63;
  int p=blockIdx.y;
  int row0 = (blockIdx.x*4+wave)*16;
  int active = (row0<NT);
  int rA = row0 + (lane&15); if(rA>NT-1) rA=NT-1;
  const short* arowb = stb + (size_t)p*NT*512 + (size_t)rA*512 + ((lane>>4)<<3);
  const float* arowf = stf + (size_t)p*NT*512 + (size_t)rA*512 + ((lane>>4)<<3);
  f32x4 acc[8];
  #pragma unroll
  for(int c=0;c<8;c++) acc[c]=(f32x4){0.f,0.f,0.f,0.f};
  const short8* bp = (const short8*)bpk;
  if(active){
    for(int kt=0;kt<16;kt++){
      short8 a;
      if(isbf){
        a = *(const short8*)(arowb + kt*32);
      } else {
        float4 f0 = *(const float4*)(arowf + kt*32);
        float4 f1 = *(const float4*)(arowf + kt*32 + 4);
        a[0]=f2bf(f0.x); a[1]=f2bf(f0.y); a[2]=f2bf(f0.z); a[3]=f2bf(f0.w);
        a[4]=f2bf(f1.x); a[5]=f2bf(f1.y); a[6]=f2bf(f1.z); a[7]=f2bf(f1.w);
      }
      const short8* bk = bp + (size_t)kt*512 + lane;
      #pragma unroll
      for(int c=0;c<8;c++){
        short8 bfr = bk[c*64];              // coalesced 1KB/wave, L2-hit
        acc[c]=__builtin_amdgcn_mfma_f32_16x16x32_bf16(a,bfr,acc[c],0,0,0);
      }
    }
  }
  int rbase = row0 + ((lane>>4)<<2);
  int colb = lane&15;
  float sc[8];
  #pragma unroll
  for(int c=0;c<8;c++){
    float s=0.f;
    if(active){
      float bb=bias[c*16+colb];
      #pragma unroll
      for(int r=0;r<4;r++){
        if(rbase+r<NT) s += fast_tanh(acc[c][r]+bb);
      }
    }
    s += __shfl_xor(s,16,64);
    s += __shfl_xor(s,32,64);
    sc[c]=s;
  }
  if(lane<16){
    #pragma unroll
    for(int c=0;c<8;c++) red[wave][c*16+lane]=sc[c];
  }
  __syncthreads();
  if(threadIdx.x<128){
    float t = red[0][threadIdx.x]+red[1][threadIdx.x]+red[2][threadIdx.x]+red[3][threadIdx.x];
    atomicAdd(&accv_s[p*128+threadIdx.x], t);
  }
}

// -------- final: logits[t] = (b0*st0[row]+b1*st1[row]) @ lW1 + lb1 -----------------
__global__ __launch_bounds__(64) void k_final(const float* __restrict__ st0, const float* __restrict__ st1,
      const float* __restrict__ accv_s, const float* __restrict__ q,
      const float* __restrict__ lW1, const float* __restrict__ lb1,
      const int* __restrict__ tgt, float* __restrict__ out){
  int t=blockIdx.x; int lane=threadIdx.x;
  int row=tgt[t];
  float b0, b1;
  compute_beta(accv_s, q, &b0, &b1);
  float acc[8]={0.f,0.f,0.f,0.f,0.f,0.f,0.f,0.f};
  #pragma unroll
  for(int kk=0;kk<8;kk++){
    int k=kk*64+lane;
    float hm=b0*st0[(size_t)row*512+k]+b1*st1[(size_t)row*512+k];
    const float4* wp=(const float4*)(lW1+(size_t)k*8);
    float4 w0=wp[0], w1=wp[1];
    acc[0]+=hm*w0.x; acc[1]+=hm*w0.y; acc[2]+=hm*w0.z; acc[3]+=hm*w0.w;
    acc[4]+=hm*w1.x; acc[5]+=hm*w1.y; acc[6]+=hm*w1.z; acc[7]+=hm*w1.w;
  }
  #pragma unroll
  for(int c=0;c<8;c++){
    #pragma unroll
    for(int off=32;off>0;off>>=1) acc[c]+=__shfl_xor(acc[c],off,64);
  }
  if(lane<8){
    float v=0.f;
    #pragma unroll
    for(int c=0;c<8;c++) if(lane==c) v=acc[c];
    out[t*8+lane]=v+lb1[lane];
  }
}

extern "C" void kernel_launch(void* const* d_in, const int* in_sizes, int n_in,
                              void* d_out, int out_size, void* d_ws, size_t ws_size,
                              hipStream_t stream) {
  const float* X0=(const float*)d_in[0];
  const float* X1=(const float*)d_in[1];
  const float* X2=(const float*)d_in[2];
  const float* fcW0=(const float*)d_in[3]; const float* fcb0=(const float*)d_in[4];
  const float* fcW1=(const float*)d_in[5]; const float* fcb1=(const float*)d_in[6];
  const float* fcW2=(const float*)d_in[7]; const float* fcb2=(const float*)d_in[8];
  const float* attn1=(const float*)d_in[9];
  const float* attn2=(const float*)d_in[10];
  const float* mpW=(const float*)d_in[11];
  const float* mpb=(const float*)d_in[12];
  const float* mpq=(const float*)d_in[13];
  const float* lW0=(const float*)d_in[14]; const float* lb0=(const float*)d_in[15];
  const float* lW1=(const float*)d_in[16]; const float* lb1=(const float*)d_in[17];
  const int* mp=(const int*)d_in[18];
  const int* tgt=(const int*)d_in[19];
  float* out=(float*)d_out;

  // workspace layout (total ~273.6 MB). Liveness-checked carve-outs:
  char* ws=(char*)d_ws;
  float* h0   =(float*)(ws+0);              // N*64 f32      (live from k_scmm on)
  float* h1   =(float*)(ws+26112000);       // N*64 f32
  float* ptab =(float*)(ws+52224000);       // 6*N*16 f32
  int*   offs =(int*  )(ws+91392000);       // 6*(NT+1)
  int*   counts=(int* )(ws+92208128);       // 6*NT (live through k_scmm scatter part)
  int2*  mids =(int2* )(ws+100224128);      // 6*E int2 = 14.4 MB
  short* hb   =(short*)(ws+114624128);      // N*64 bf16 = 13.056 MB
  // packed fc weights AFTER hb (counts must stay live past packWall for k_scmm)
  short* wpk0 =(short*)(ws+127680128);      // +128KB  K=512
  short* wpk1 =(short*)(ws+127811200);      // +64KB   K=256
  short* wpkL =(short*)(ws+127876736);      // +128KB  K=512
  short* wpk2 =(short*)(ws+128007808);      // +32KB   K=128
  // st region: bf16 st (layer 0) / f32 st (layer 1) share (sequential liveness)
  short* stb  =(short*)(ws+133824128);      // 2*NT*512 bf16 (layer 0)
  float* stf  =(float*)(ws+133824128);      // 2*NT*512 f32  (layer 1)
  short* bpk4 =(short*)(ws+273088128);      // 4 packed mpW mats, 512 KB
  float* accv =(float*)(ws+273612416);      // 4 slots x 256 f32
  // bsum: used ONLY during CSR build; placed in st region (first written by k_seg later)
  int*   bsum =(int*  )(ws+133824128);      // 6*NBLK ints = 3192 B

  dim3 b256(256);
  // CSR build prefix (mp_idx is layer-invariant; built once per launch)
  k_zero<<<dim3((6*NT+255)/256),b256,0,stream>>>(counts,6*NT);
  k_hist<<<dim3((NE+255)/256,6),b256,0,stream>>>(mp,counts);
  k_blkred<<<dim3(NBLK,6),b256,0,stream>>>(counts,bsum);
  k_scansums<<<dim3(6),b256,0,stream>>>(bsum);
  k_scanapply<<<dim3(NBLK,6),b256,0,stream>>>(counts,bsum,offs);

  // pack fc weights + all 4 mpW mats + zero accv
  k_packWall<<<dim3(32,8),b256,0,stream>>>(fcW0,fcW1,fcW2,lW0,mpW,wpk0,wpk1,wpk2,wpkL,bpk4,accv);

  // FUSED: edge scatter + per-type feature transforms (h0 f32 + hb bf16 shadow)
  k_scmm<<<dim3(320*27),b256,0,stream>>>(mp,offs,counts,mids,X0,X1,X2,
                                         wpk0,wpk1,wpk2,fcb0,fcb1,fcb2,h0,hb);

  // ---- layer 0 (st in bf16) ----
  k_pre<<<dim3((NN+255)/256),b256,0,stream>>>(h0,attn1,attn2,ptab,6,(short*)nullptr);
  for(int type=0;type<3;type++){
    k_seg<<<dim3(NT/4,2),b256,0,stream>>>(offs,ptab,mids,h0,hb,stb,stf,type,1);
    k_tanhmm<<<dim3(532,2),b256,0,stream>>>(stb,stf,1,bpk4+(size_t)type*65536,
                                            mpb+(0*3+type)*128,accv+type*256);
    k_mm64fB<<<dim3(532),b256,0,stream>>>(stb,stb+(size_t)NT*512,accv+type*256,mpq+(0*3+type)*128,
                                          wpkL,lb0,h1+(size_t)type*NT*64,NT,1);
  }

  // ---- layer 1 (st in f32; only type 0 reaches the output) ----
  // k_pre also writes hb = bf16(h1) (row already in registers) -> k_cvt eliminated
  k_pre<<<dim3((NN+255)/256),b256,0,stream>>>(h1,attn1+(size_t)6*512,attn2+(size_t)6*512,ptab,2,hb);
  k_seg<<<dim3(NT/4,2),b256,0,stream>>>(offs,ptab,mids,h1,hb,stb,stf,0,0);
  k_tanhmm<<<dim3(532,2),b256,0,stream>>>(stb,stf,0,bpk4+(size_t)3*65536,
                                          mpb+(1*3+0)*128,accv+3*256);
  k_final<<<dim3(NTGT),dim3(64),0,stream>>>(stf,stf+(size_t)NT*512,accv+3*256,mpq+(1*3+0)*128,
                                            lW1,lb1,tgt,out);
}